// Round 7
// baseline (226.157 us; speedup 1.0000x reference)
//
#include <hip/hip_runtime.h>

#define NF    25     // input features per row
#define NPAIR 300    // upper-triangle pairs (25*24/2)
#define NCOL  425    // output cols: 25*5 + 300
#define ROWS  8      // rows staged per block-chunk
#define BLK   256
#define TILE4 (ROWS * NCOL / 4)   // 850 float4s per chunk (13600 B, 16B-aligned)

typedef float f32x4 __attribute__((ext_vector_type(4)));

__global__ __launch_bounds__(BLK) void feat_expand_kernel(
    const float* __restrict__ x, float* __restrict__ out,
    int nrows, int nchunks) {
  __shared__ f32x4 tile4[TILE4];            // 13600 B, 16B-aligned
  __shared__ float  xs[ROWS * NF];          // 800 B
  __shared__ unsigned short pairs[NPAIR];   // 600 B
  float* tile = (float*)tile4;

  const int tid = threadIdx.x;

  // (i,j) pair table, row-major upper triangle. NPAIR > BLK: stride it.
  for (int p = tid; p < NPAIR; p += BLK) {
    int rem = p, i = 0;
    while (rem >= (NF - 1 - i)) { rem -= (NF - 1 - i); ++i; }
    pairs[p] = (unsigned short)(i | ((i + 1 + rem) << 8));
  }

  for (int chunk = blockIdx.x; chunk < nchunks; chunk += gridDim.x) {
    const long long rowbase = (long long)chunk * ROWS;
    const int rows_here = (int)((nrows - rowbase) < ROWS ? (nrows - rowbase) : ROWS);

    __syncthreads();  // protect xs/tile from previous iteration's readers

    // Phase A: stage 200 input floats, coalesced
    if (tid < ROWS * NF) {
      const int r = tid / NF;
      if (r < rows_here) xs[tid] = x[rowbase * NF + tid];
    }
    __syncthreads();

    // Phase B1: unary features — one thread per (row, input col), branch-free.
    if (tid < ROWS * NF) {
      const int r = tid / NF, i = tid - r * NF;
      if (r < rows_here) {
        float* tr = &tile[r * NCOL];
        const float v  = xs[tid];
        const float ax = fabsf(v) + 1e-10f;
        const float l2 = __builtin_amdgcn_logf(ax);      // v_log_f32: log2(ax)
        tr[i]          = v;                              // identity
        tr[NF + i]     = v * v;                          // square
        tr[2*NF + i]   = l2 * 0.69314718055994530942f;   // ln = log2*ln2
        tr[3*NF + i]   = sqrtf(ax);                      // v_sqrt_f32
        tr[4*NF + i]   = __builtin_amdgcn_exp2f(l2 * (1.0f/3.0f)); // cbrt
      }
    }
    // Phase B2: pairwise products, flat strided, branch-free
    for (int p = tid; p < ROWS * NPAIR; p += BLK) {
      const int r = p / NPAIR, q = p - r * NPAIR;
      if (r < rows_here) {
        const unsigned short pr = pairs[q];
        tile[r * NCOL + 5*NF + q] =
            xs[r * NF + (pr & 0xFF)] * xs[r * NF + (pr >> 8)];
      }
    }
    __syncthreads();

    // Phase C: copy tile -> global as aligned float4 REGULAR stores
    // (single-variable change vs round 4: no nontemporal hint — the memset
    //  that hits 6.7 TB/s uses regular stores; full-line writes -> no RFO)
    if (rows_here == ROWS) {
      f32x4* __restrict__ o4 = (f32x4*)(out + rowbase * NCOL);
      for (int v = tid; v < TILE4; v += BLK)
        o4[v] = tile4[v];
    } else {  // tail chunk (not hit at 524288 rows, kept for correctness)
      const int total = rows_here * NCOL;
      for (int o = tid; o < total; o += BLK)
        out[rowbase * NCOL + o] = tile[o];
    }
  }
}

extern "C" void kernel_launch(void* const* d_in, const int* in_sizes, int n_in,
                              void* d_out, int out_size, void* d_ws, size_t ws_size,
                              hipStream_t stream) {
  const float* x = (const float*)d_in[0];
  float* out = (float*)d_out;

  const int nrows = in_sizes[0] / NF;                 // 524288
  const int nchunks = (nrows + ROWS - 1) / ROWS;      // 65536
  const int grid = nchunks < 4096 ? nchunks : 4096;

  feat_expand_kernel<<<grid, BLK, 0, stream>>>(x, out, nrows, nchunks);
}

// Round 8
// 224.117 us; speedup vs baseline: 1.0091x; 1.0091x over previous
//
#include <hip/hip_runtime.h>

#define NF     25                  // input features per row
#define NUNARY 125                 // unary outputs per row (5*25)
#define NCOL   425                 // output cols per row
#define WROWS  4                   // rows per WAVE-chunk
#define BLK    256
#define WAVES  (BLK / 64)
#define WXS    (WROWS * NF)        // 100 staged x per wave
#define WVALS  608                 // per-wave vals slots (100 + 500 + 1 + pad)
#define ONE_OFF 600                // vals[ONE_OFF] == 1.0f
#define TILE_DW (WROWS * NCOL)     // 1700 output dwords per wave-chunk
#define TILE4   (TILE_DW / 4)      // 425 float4s

typedef float f32x4 __attribute__((ext_vector_type(4)));
typedef unsigned int u32;
typedef u32 u32x4 __attribute__((ext_vector_type(4)));

__global__ __launch_bounds__(BLK) void feat_expand_kernel(
    const float* __restrict__ x, float* __restrict__ out,
    int nrows, int nwchunks) {
  __shared__ u32x4 dtab4[TILE4];           // 6800 B, shared read-only desc
  __shared__ float vals[WAVES * WVALS];    // 9728 B, wave-private slices
  u32* dtab = (u32*)dtab4;

  const int tid  = threadIdx.x;
  const int wid  = tid >> 6;
  const int lane = tid & 63;
  float* wv = &vals[wid * WVALS];

  // One-time: desc table (out_dword(o) = vals[dA] * vals[dB]) + 1.0 slots
  for (int o = tid; o < TILE_DW; o += BLK) {
    const int r = o / NCOL, c = o - r * NCOL;
    u32 d;
    if (c < NUNARY) {
      d = (u32)(WXS + r * NUNARY + c) | ((u32)ONE_OFF << 16);
    } else {
      int rem = c - NUNARY, i = 0;
      while (rem >= (NF - 1 - i)) { rem -= (NF - 1 - i); ++i; }
      d = (u32)(r * NF + i) | ((u32)(r * NF + i + 1 + rem) << 16);
    }
    dtab[o] = d;
  }
  if (lane == 0) wv[ONE_OFF] = 1.0f;
  __syncthreads();   // the ONLY block barrier — hot loop below is barrier-free

  const int gwaves = gridDim.x * WAVES;
  for (int wc = blockIdx.x * WAVES + wid; wc < nwchunks; wc += gwaves) {
    const long long rowbase = (long long)wc * WROWS;
    const long long remr = nrows - rowbase;
    const int rows_here = (int)(remr < WROWS ? remr : WROWS);

    // Stage x + unary features into the wave-private slice.
    // In-wave DS ordering (lgkmcnt) is the only sync needed.
#pragma unroll
    for (int k = 0; k < 2; ++k) {
      const int idx = lane + k * 64;           // covers 0..99
      const int r = idx / NF, i = idx - r * NF;
      if (idx < WXS && r < rows_here) {
        const float v = x[rowbase * NF + idx];
        wv[idx] = v;
        float* ur = &wv[WXS + r * NUNARY];
        const float ax = fabsf(v) + 1e-10f;
        const float l2 = __builtin_amdgcn_logf(ax);        // v_log_f32
        ur[i]          = v;                                // identity
        ur[NF + i]     = v * v;                            // square
        ur[2*NF + i]   = l2 * 0.69314718055994530942f;     // ln
        ur[3*NF + i]   = sqrtf(ax);                        // sqrt
        ur[4*NF + i]   = __builtin_amdgcn_exp2f(l2 * (1.0f/3.0f)); // cbrt
      }
    }

    if (rows_here == WROWS) {
      f32x4* o4 = (f32x4*)(out + rowbase * NCOL);
#pragma unroll
      for (int k = 0; k < 7; ++k) {
        const int v4 = lane + k * 64;          // 425 = 6*64 + 41
        if (k < 6 || v4 < TILE4) {
          const u32x4 d = dtab4[v4];
          f32x4 ov;
          ov.x = wv[d.x & 0xFFFF] * wv[d.x >> 16];
          ov.y = wv[d.y & 0xFFFF] * wv[d.y >> 16];
          ov.z = wv[d.z & 0xFFFF] * wv[d.z >> 16];
          ov.w = wv[d.w & 0xFFFF] * wv[d.w >> 16];
          __builtin_nontemporal_store(ov, &o4[v4]);
        }
      }
    } else {  // tail wave-chunk (not hit when nrows % WROWS == 0)
      const int total = rows_here * NCOL;
      for (int o = lane; o < total; o += 64) {
        const u32 d = dtab[o];
        out[rowbase * NCOL + o] = wv[d & 0xFFFF] * wv[d >> 16];
      }
    }
  }
}

extern "C" void kernel_launch(void* const* d_in, const int* in_sizes, int n_in,
                              void* d_out, int out_size, void* d_ws, size_t ws_size,
                              hipStream_t stream) {
  const float* x = (const float*)d_in[0];
  float* out = (float*)d_out;

  const int nrows = in_sizes[0] / NF;                      // 524288
  const int nwchunks = (nrows + WROWS - 1) / WROWS;        // 131072
  const int nblocks = (nwchunks + WAVES - 1) / WAVES;      // 32768
  const int grid = nblocks < 4096 ? nblocks : 4096;        // known-good grid

  feat_expand_kernel<<<grid, BLK, 0, stream>>>(x, out, nrows, nwchunks);
}

// Round 9
// 208.524 us; speedup vs baseline: 1.0846x; 1.0748x over previous
//
#include <hip/hip_runtime.h>

#define NF    25     // input features per row
#define NPAIR 300    // upper-triangle pairs (25*24/2)
#define NCOL  425    // output cols: 25*5 + 300
#define ROWS  8      // rows staged per block-chunk
#define BLK   256
#define TILE4 (ROWS * NCOL / 4)       // 850 float4s (13600 B)
#define NP_TOT (ROWS * NPAIR)         // 2400 pair products per chunk
#define KFULL  (NP_TOT / BLK)         // 9 full passes
#define KREM   (NP_TOT - KFULL * BLK) // 96 tail threads

typedef float f32x4 __attribute__((ext_vector_type(4)));
typedef unsigned int u32;

__global__ __launch_bounds__(BLK) void feat_expand_kernel(
    const float* __restrict__ x, float* __restrict__ out,
    int nrows, int nchunks) {
  __shared__ f32x4 tile4[TILE4];            // 13600 B
  __shared__ float xs[ROWS * NF];           // 800 B
  float* tile = (float*)tile4;

  const int tid = threadIdx.x;
  const int r200 = tid / NF, i200 = tid - r200 * NF;

  // ---- Hoisted static B2 descriptors (chunk-independent!) ----
  // Pass k: thread handles flat pair p = tid + k*256 -> (row r, pair q).
  // ab[k] packs the two xs dword-indices; ti[k] is the tile dword-index.
  u32 ab[KFULL + 1];
  u32 ti[KFULL + 1];
#pragma unroll
  for (int k = 0; k <= KFULL; ++k) {
    int p = tid + k * BLK;
    if (p >= NP_TOT) p = 0;                 // dummy; write is predicated off
    const int r = p / NPAIR;
    const int q = p - r * NPAIR;
    int rem = q, i = 0;
    while (rem >= (NF - 1 - i)) { rem -= (NF - 1 - i); ++i; }
    const int j = i + 1 + rem;
    ab[k] = (u32)(r * NF + i) | ((u32)(r * NF + j) << 16);
    ti[k] = (u32)(r * NCOL + 5 * NF + q);
  }

  for (int chunk = blockIdx.x; chunk < nchunks; chunk += gridDim.x) {
    const long long rowbase = (long long)chunk * ROWS;
    const long long remr = nrows - rowbase;
    const int rows_here = (int)(remr < ROWS ? remr : ROWS);

    // Phase A: load own element into register, publish to xs
    float v = 0.0f;
    if (tid < ROWS * NF) {
      if (r200 < rows_here) v = x[rowbase * NF + tid];
      xs[tid] = v;
    }
    __syncthreads();  // xs ready; also: all waves finished prev C (tile free)

    // Phase B1: unary features from the register (no xs re-read)
    if (tid < ROWS * NF) {
      float* tr = &tile[r200 * NCOL];
      const float ax = fabsf(v) + 1e-10f;
      const float l2 = __builtin_amdgcn_logf(ax);        // v_log_f32: log2
      tr[i200]        = v;                               // identity
      tr[NF + i200]   = v * v;                           // square
      tr[2*NF + i200] = l2 * 0.69314718055994530942f;    // ln = log2*ln2
      tr[3*NF + i200] = sqrtf(ax);                       // v_sqrt_f32
      tr[4*NF + i200] = __builtin_amdgcn_exp2f(l2 * (1.0f/3.0f)); // cbrt
    }

    // Phase B2: pair products — pure {2x ds_read, mul, ds_write} per pass,
    // zero table reads, zero index decode (all static, in registers)
#pragma unroll
    for (int k = 0; k <= KFULL; ++k) {
      if (k < KFULL || tid < KREM) {
        const u32 d = ab[k];
        tile[ti[k]] = xs[d & 0xFFFF] * xs[d >> 16];
      }
    }
    __syncthreads();  // tile ready

    // Phase C: aligned float4 nt-stores (850 = 3*256 + 82)
    if (rows_here == ROWS) {
      f32x4* __restrict__ o4 = (f32x4*)(out + rowbase * NCOL);
#pragma unroll
      for (int k = 0; k < 4; ++k) {
        const int v4 = tid + k * BLK;
        if (k < 3 || v4 < TILE4)
          __builtin_nontemporal_store(tile4[v4], &o4[v4]);
      }
    } else {  // tail chunk (not hit when nrows % ROWS == 0)
      const int total = rows_here * NCOL;
      for (int o = tid; o < total; o += BLK)
        out[rowbase * NCOL + o] = tile[o];
    }
  }
}

extern "C" void kernel_launch(void* const* d_in, const int* in_sizes, int n_in,
                              void* d_out, int out_size, void* d_ws, size_t ws_size,
                              hipStream_t stream) {
  const float* x = (const float*)d_in[0];
  float* out = (float*)d_out;

  const int nrows = in_sizes[0] / NF;                 // 524288
  const int nchunks = (nrows + ROWS - 1) / ROWS;      // 65536
  const int grid = nchunks < 4096 ? nchunks : 4096;

  feat_expand_kernel<<<grid, BLK, 0, stream>>>(x, out, nrows, nchunks);
}

// Round 10
// 205.976 us; speedup vs baseline: 1.0980x; 1.0124x over previous
//
#include <hip/hip_runtime.h>

#define NF    25     // input features per row
#define NPAIR 300    // upper-triangle pairs (25*24/2)
#define NCOL  425    // output cols: 25*5 + 300
#define ROWS  8      // rows per chunk
#define BLK   256
#define TILE4N 850                // float4s per chunk (13600 B)
#define NP_TOT (ROWS * NPAIR)     // 2400 pair products per chunk
#define KFULL  (NP_TOT / BLK)     // 9 full passes
#define KREM   (NP_TOT - KFULL * BLK) // 96 tail threads

typedef float f32x4 __attribute__((ext_vector_type(4)));
typedef unsigned int u32;

__global__ __launch_bounds__(BLK) void feat_expand_kernel(
    const float* __restrict__ x, float* __restrict__ out,
    int nrows, int nchunks) {
  // Double-buffered: window w = { C-store(chunk) from tile[par],
  //   B-compute(chunk+G) into tile[par^1] from xs[par^1],
  //   A-load(chunk+2G) into xs[par] }  -- all buffer-disjoint, 1 barrier/window.
  __shared__ f32x4 tile4[2][TILE4N];        // 27200 B
  __shared__ float xs[2][ROWS * NF];        // 1600 B

  const int tid = threadIdx.x;
  const int r200 = tid / NF, i200 = tid - r200 * NF;

  // Hoisted static B2 descriptors (chunk-independent), as in round 9
  u32 ab[KFULL + 1];
  u32 ti[KFULL + 1];
#pragma unroll
  for (int k = 0; k <= KFULL; ++k) {
    int p = tid + k * BLK;
    if (p >= NP_TOT) p = 0;                 // dummy; predicated off at use
    const int r = p / NPAIR;
    const int q = p - r * NPAIR;
    int rem = q, i = 0;
    while (rem >= (NF - 1 - i)) { rem -= (NF - 1 - i); ++i; }
    ab[k] = (u32)(r * NF + i) | ((u32)(r * NF + i + 1 + rem) << 16);
    ti[k] = (u32)(r * NCOL + 5 * NF + q);
  }

  const long long G  = gridDim.x;
  const long long c0 = blockIdx.x;

  auto stageA = [&](int b, long long cc) {   // x(chunk cc) -> xs[b]
    if (tid < ROWS * NF) {
      const long long rowbase = cc * ROWS;
      float v = 0.0f;
      if (rowbase + r200 < nrows) v = x[rowbase * NF + tid];
      xs[b][tid] = v;
    }
  };
  auto stageB = [&](int bt, int bx) {        // tile[bt] <- features(xs[bx])
    float* tile = (float*)tile4[bt];
    if (tid < ROWS * NF) {
      const float v = xs[bx][tid];
      float* tr = &tile[r200 * NCOL];
      const float ax = fabsf(v) + 1e-10f;
      const float l2 = __builtin_amdgcn_logf(ax);        // v_log_f32: log2
      tr[i200]        = v;                               // identity
      tr[NF + i200]   = v * v;                           // square
      tr[2*NF + i200] = l2 * 0.69314718055994530942f;    // ln = log2*ln2
      tr[3*NF + i200] = sqrtf(ax);                       // v_sqrt_f32
      tr[4*NF + i200] = __builtin_amdgcn_exp2f(l2 * (1.0f/3.0f)); // cbrt
    }
#pragma unroll
    for (int k = 0; k <= KFULL; ++k) {
      if (k < KFULL || tid < KREM) {
        const u32 d = ab[k];
        tile[ti[k]] = xs[bx][d & 0xFFFF] * xs[bx][d >> 16];
      }
    }
  };

  // Prologue: fill pipeline (tile[0] = chunk c0; xs[1] = chunk c0+G)
  if (c0 < nchunks) stageA(0, c0);
  __syncthreads();
  if (c0 < nchunks) stageB(0, 0);
  if (c0 + G < nchunks) stageA(1, c0 + G);
  __syncthreads();

  int par = 0;
  for (long long chunk = c0; chunk < nchunks; chunk += G, par ^= 1) {
    // C: store chunk from tile[par] (nt, float4, 850 = 3*256 + 82)
    const long long rowbase = chunk * ROWS;
    const long long remr = nrows - rowbase;
    const int rows_here = (int)(remr < ROWS ? remr : ROWS);
    if (rows_here == ROWS) {
      f32x4* __restrict__ o4 = (f32x4*)(out + rowbase * NCOL);
#pragma unroll
      for (int k = 0; k < 4; ++k) {
        const int v4 = tid + k * BLK;
        if (k < 3 || v4 < TILE4N)
          __builtin_nontemporal_store(tile4[par][v4], &o4[v4]);
      }
    } else {  // tail chunk (not hit when nrows % ROWS == 0)
      const float* tile = (const float*)tile4[par];
      const int total = rows_here * NCOL;
      for (int o = tid; o < total; o += BLK)
        out[rowbase * NCOL + o] = tile[o];
    }

    // B: compute next chunk's tile; A: load chunk after next. Disjoint buffers.
    if (chunk + G < nchunks)     stageB(par ^ 1, par ^ 1);
    if (chunk + 2*G < nchunks)   stageA(par, chunk + 2*G);
    __syncthreads();
  }
}

extern "C" void kernel_launch(void* const* d_in, const int* in_sizes, int n_in,
                              void* d_out, int out_size, void* d_ws, size_t ws_size,
                              hipStream_t stream) {
  const float* x = (const float*)d_in[0];
  float* out = (float*)d_out;

  const int nrows = in_sizes[0] / NF;                 // 524288
  const int nchunks = (nrows + ROWS - 1) / ROWS;      // 65536
  const int grid = nchunks < 4096 ? nchunks : 4096;

  feat_expand_kernel<<<grid, BLK, 0, stream>>>(x, out, nrows, nchunks);
}